// Round 1
// baseline (157.305 us; speedup 1.0000x reference)
//
#include <hip/hip_runtime.h>
#include <cstdint>
#include <cstddef>

#define NAGENT 64
#define WAVES_PER_BLOCK 4
#define ROWCAP 640   // >= 630 max directed edges per batch, padded for alignment

// ---------------------------------------------------------------------------
// Kernel 1: x = concat([obs, init], -1).reshape(B*N, 18)
// ---------------------------------------------------------------------------
__global__ __launch_bounds__(256) void x_concat_kernel(
    const float* __restrict__ obs, const float* __restrict__ ego,
    const float* __restrict__ oth, float* __restrict__ out, int total)
{
    int i = blockIdx.x * blockDim.x + threadIdx.x;
    if (i >= total) return;
    unsigned int ui = (unsigned int)i;
    unsigned int q = ui / 18u;          // row = b*64 + n
    unsigned int r = ui - q * 18u;      // col
    float v;
    if (r < 16u) {
        v = obs[(size_t)q * 16u + r];
    } else {
        const float* ini = ((q & 63u) == 0u) ? ego : oth;
        v = ini[r - 16u];
    }
    out[i] = v;
}

// ---------------------------------------------------------------------------
// Kernel 2: per-batch edge construction. One wave (64 lanes) per batch.
// Builds a 64x64 adjacency bitmask in LDS (dedupe + lexsort for free),
// then writes compacted (src,dst) lists + count to workspace.
// ---------------------------------------------------------------------------
__global__ __launch_bounds__(64 * WAVES_PER_BLOCK) void build_edges_kernel(
    const float* __restrict__ obs, int* __restrict__ e_src,
    int* __restrict__ e_dst, int* __restrict__ counts, int B)
{
    const int wave = threadIdx.x >> 6;
    const int lane = threadIdx.x & 63;
    const int b = blockIdx.x * WAVES_PER_BLOCK + wave;
    if (blockIdx.x * WAVES_PER_BLOCK >= B) return;   // whole-block guard (never taken for B%4==0)

    __shared__ int   order_s[WAVES_PER_BLOCK][NAGENT];
    __shared__ float ys_s[WAVES_PER_BLOCK][NAGENT];
    __shared__ unsigned int adj_s[WAVES_PER_BLOCK][NAGENT][2];

    // Load this agent's (x, y)
    const size_t rowbase = ((size_t)b * NAGENT + lane) * 16u;
    float x = obs[rowbase + 0];
    float y = obs[rowbase + 1];

    // Stable rank by x (tie-break: original index) — all-pairs via shfl
    int rank = 0;
    #pragma unroll 8
    for (int j = 0; j < 64; ++j) {
        float xj = __shfl(x, j);
        rank += (xj < x || (xj == x && j < lane)) ? 1 : 0;
    }
    order_s[wave][rank] = lane;   // sorted position -> agent id
    ys_s[wave][lane] = y;
    adj_s[wave][lane][0] = 0u;
    adj_s[wave][lane][1] = 0u;
    __syncthreads();

    // Lane = sorted position p. Compute the 5 lane-band masks for agent at p.
    const int a = order_s[wave][lane];
    const float ya = ys_s[wave][a];
    const float T1 = 1.0f / 3.0f;   // 0x3EAAAAAB, matches jnp f32 cast of 1/3
    const float T2 = 2.0f / 3.0f;   // 0x3F2AAAAB, matches jnp f32 cast of 2*(1/3)
    const bool m0 = (ya <= T1) && (ya > 0.0f);
    const bool m1 = (ya > T1) && (ya <= T2);
    const bool m2 = (ya >= T2) && (ya < 1.0f);
    bool ms[5];
    ms[0] = m0; ms[1] = m1; ms[2] = m2; ms[3] = m0 || m1; ms[4] = m1 || m2;

    // For each mask: connect consecutive members (in x order) bidirectionally.
    #pragma unroll
    for (int k = 0; k < 5; ++k) {
        unsigned long long bits = __ballot(ms[k]);
        unsigned long long higher = (lane == 63) ? 0ULL : (bits >> (lane + 1));
        if (ms[k] && higher != 0ULL) {
            int q = lane + 1 + __builtin_ctzll(higher);   // next mask member position
            int bb = order_s[wave][q];
            atomicOr(&adj_s[wave][a][bb >> 5], 1u << (bb & 31));
            atomicOr(&adj_s[wave][bb][a >> 5], 1u << (a & 31));
        }
    }
    __syncthreads();

    // Row-major bit enumeration = unique edges sorted by (src, dst).
    unsigned int r0 = adj_s[wave][lane][0];
    unsigned int r1 = adj_s[wave][lane][1];
    const int c = __popc(r0) + __popc(r1);

    // Inclusive wave prefix sum of row counts
    int pre = c;
    #pragma unroll
    for (int off = 1; off < 64; off <<= 1) {
        int t = __shfl_up(pre, off);
        if (lane >= off) pre += t;
    }
    const int rowstart = pre - c;
    if (lane == 63) counts[b] = pre;   // total edges this batch

    const int base = b * ROWCAP;
    const int sg = b * NAGENT + lane;  // global src id
    int idx = base + rowstart;
    while (r0) {
        int d = __builtin_ctz(r0); r0 &= r0 - 1u;
        e_src[idx] = sg; e_dst[idx] = b * NAGENT + d; ++idx;
    }
    while (r1) {
        int d = 32 + __builtin_ctz(r1); r1 &= r1 - 1u;
        e_src[idx] = sg; e_dst[idx] = b * NAGENT + d; ++idx;
    }
}

// ---------------------------------------------------------------------------
// Kernel 3: exclusive prefix sum of per-batch counts (single block).
// offsets[B] = total edge count E.
// ---------------------------------------------------------------------------
__global__ __launch_bounds__(256) void scan_kernel(
    const int* __restrict__ counts, int* __restrict__ offsets, int B)
{
    __shared__ int part[256];
    const int t = threadIdx.x;
    const int per = (B + 255) / 256;
    const int beg = t * per;
    int s = 0;
    for (int i = 0; i < per; ++i) { int k = beg + i; if (k < B) s += counts[k]; }
    part[t] = s;
    __syncthreads();
    for (int off = 1; off < 256; off <<= 1) {
        int v = (t >= off) ? part[t - off] : 0;
        __syncthreads();
        part[t] += v;
        __syncthreads();
    }
    int run = part[t] - s;   // exclusive base for this thread's chunk
    for (int i = 0; i < per; ++i) {
        int k = beg + i;
        if (k < B) { offsets[k] = run; run += counts[k]; }
    }
    if (t == 255) offsets[B] = run;   // total E
}

// ---------------------------------------------------------------------------
// Kernel 4: fill padding region [E, slots) with -1 in both rows.
// ---------------------------------------------------------------------------
__global__ __launch_bounds__(256) void pad_fill_kernel(
    float* __restrict__ out_es, float* __restrict__ out_ed,
    const int* __restrict__ offsets, int B, int slots)
{
    const int E = offsets[B];
    int i = blockIdx.x * blockDim.x + threadIdx.x;
    if (i < slots && i >= E) {
        out_es[i] = -1.0f;
        out_ed[i] = -1.0f;
    }
}

// ---------------------------------------------------------------------------
// Kernel 5: scatter per-batch compacted edges to global offsets (as floats).
// ---------------------------------------------------------------------------
__global__ __launch_bounds__(256) void emit_kernel(
    const int* __restrict__ e_src, const int* __restrict__ e_dst,
    const int* __restrict__ counts, const int* __restrict__ offsets,
    float* __restrict__ out_es, float* __restrict__ out_ed)
{
    const int b = blockIdx.x;
    const int cnt = counts[b];
    const int off = offsets[b];
    const int base = b * ROWCAP;
    for (int j = threadIdx.x; j < cnt; j += blockDim.x) {
        out_es[off + j] = (float)e_src[base + j];
        out_ed[off + j] = (float)e_dst[base + j];
    }
}

// ---------------------------------------------------------------------------
extern "C" void kernel_launch(void* const* d_in, const int* in_sizes, int n_in,
                              void* d_out, int out_size, void* d_ws, size_t ws_size,
                              hipStream_t stream)
{
    const float* obs = (const float*)d_in[0];
    const float* ego = (const float*)d_in[1];
    const float* oth = (const float*)d_in[2];

    const int B = in_sizes[0] / (NAGENT * 16);        // 8192
    const int M = B * NAGENT;                          // 524288
    const int xtotal = M * 18;                         // 9437184
    const int slots = B * 10 * (NAGENT - 1);           // 5160960

    float* out_x  = (float*)d_out;
    float* out_es = out_x + xtotal;
    float* out_ed = out_es + slots;

    // Workspace layout (ints): e_src[B*640] | e_dst[B*640] | counts[B] | offsets[B+1]
    int* e_src   = (int*)d_ws;
    int* e_dst   = e_src + (size_t)B * ROWCAP;
    int* counts  = e_dst + (size_t)B * ROWCAP;
    int* offsets = counts + B;

    x_concat_kernel<<<(xtotal + 255) / 256, 256, 0, stream>>>(obs, ego, oth, out_x, xtotal);
    build_edges_kernel<<<(B + WAVES_PER_BLOCK - 1) / WAVES_PER_BLOCK,
                         64 * WAVES_PER_BLOCK, 0, stream>>>(obs, e_src, e_dst, counts, B);
    scan_kernel<<<1, 256, 0, stream>>>(counts, offsets, B);
    pad_fill_kernel<<<(slots + 255) / 256, 256, 0, stream>>>(out_es, out_ed, offsets, B, slots);
    emit_kernel<<<B, 256, 0, stream>>>(e_src, e_dst, counts, offsets, out_es, out_ed);
}